// Round 1
// baseline (359.170 us; speedup 1.0000x reference)
//
#include <hip/hip_runtime.h>
#include <stdint.h>

typedef unsigned short u16;
typedef unsigned int   u32;

#define B_    128
#define S_    1024
#define H_    1024
#define E_    256
#define EMB_  100
#define EMBP_ 128
#define V_    50000
#define NTOK_ (B_*S_)

typedef __attribute__((ext_vector_type(8))) short bf16x8;
typedef __attribute__((ext_vector_type(4))) float f32x4;

__device__ __forceinline__ float bf2f(u16 u){ union{u32 i; float f;} c; c.i=((u32)u)<<16; return c.f; }
__device__ __forceinline__ u16 f2bf(float f){ u32 x=__float_as_uint(f); return (u16)((x + 0x7FFFu + ((x>>16)&1u))>>16); }
__device__ __forceinline__ float quantw(float w){ float r = rintf(w*16.f)*0.0625f; return fminf(fmaxf(r,-0.9375f),0.9375f); }

__device__ __forceinline__ void gll16(const void* g, void* l){
  __builtin_amdgcn_global_load_lds((const __attribute__((address_space(1))) void*)g,
                                   (__attribute__((address_space(3))) void*)l, 16, 0, 0);
}

// ---------------- prep kernels ----------------

__global__ __launch_bounds__(256) void prep_emb_k(const float* __restrict__ emb,
                                                  u16* __restrict__ hi, u16* __restrict__ lo){
  const int n = V_*EMBP_;
  for (int i = blockIdx.x*256 + threadIdx.x; i < n; i += gridDim.x*256){
    int v = i >> 7, k = i & 127;
    float val = (k < EMB_) ? emb[v*EMB_ + k] : 0.f;
    u16 h = f2bf(val);
    hi[i] = h;
    lo[i] = f2bf(val - bf2f(h));
  }
}

__global__ __launch_bounds__(256) void prep_misc_k(const float* __restrict__ W1, const float* __restrict__ W2,
    const float* __restrict__ Wr2, const float* __restrict__ b2, const float* __restrict__ br2,
    const int* __restrict__ inputs,
    u16* __restrict__ w1hi, u16* __restrict__ w1lo, u16* __restrict__ qW2,
    float* __restrict__ qWr2T, float* __restrict__ b2br2, int* __restrict__ idx2){
  const int N1 = E_*EMBP_;      // 32768  W1 split/pad
  const int N2 = H_*E_;         // 262144 qW2
  const int N3 = H_*H_;         // 1048576 qWr2T
  const int N4 = H_;            // 1024   b2+br2
  const int N5 = NTOK_;         // 131072 idx reorder
  const int total = N1+N2+N3+N4+N5;
  for (int i = blockIdx.x*256 + threadIdx.x; i < total; i += gridDim.x*256){
    int j = i;
    if (j < N1){
      int n = j >> 7, k = j & 127;
      float val = (k < EMB_) ? W1[n*EMB_ + k] : 0.f;
      u16 h = f2bf(val);
      w1hi[j] = h; w1lo[j] = f2bf(val - bf2f(h));
    } else if ((j -= N1) < N2){
      qW2[j] = f2bf(quantw(W2[j]));
    } else if ((j -= N2) < N3){
      int hp = j >> 10, h = j & 1023;
      qWr2T[j] = quantw(Wr2[h*H_ + hp]);
    } else if ((j -= N3) < N4){
      b2br2[j] = b2[j] + br2[j];
    } else {
      j -= N4;
      int s = j >> 7, b = j & 127;
      idx2[j] = inputs[b*S_ + s];      // idx2[s*128 + b]
    }
  }
}

// ---------------- tiled MFMA GEMM (128x128 tile, BK=64, 4 waves) ----------------
// C[m][n] = sum_k A[m][k]*B[n][k]   (B stored n-major, k-contiguous)
// EPI==0: out = quant_act(relu(acc + bias[n])) as bf16   (GEMM1 -> xq)
// EPI==1: out = (acc + bias[n]) as bf16                  (GEMM2 -> I)

struct GPlan { const u16* A[6]; const u16* B[6]; };

template<int EPI, bool GATHER, int NSTEPS>
__global__ __launch_bounds__(256)
void gemm_k(GPlan p, const int* __restrict__ idx, int ldA, int ldB,
            const float* __restrict__ bias, u16* __restrict__ out, int ldOut)
{
  __shared__ u16 As[128*64];
  __shared__ u16 Bs[128*64];
  const int tid = threadIdx.x;
  const int m0 = blockIdx.x * 128, n0 = blockIdx.y * 128;
  const int l = tid & 63, wid = tid >> 6;
  const int wm = wid >> 1, wn = wid & 1;

  f32x4 acc[4][4];
  #pragma unroll
  for (int a = 0; a < 4; ++a)
    #pragma unroll
    for (int c = 0; c < 4; ++c)
      acc[a][c] = (f32x4)0.f;

  #pragma unroll
  for (int st = 0; st < NSTEPS; ++st){
    const u16* Ab = p.A[st];
    const u16* Bb = p.B[st];
    #pragma unroll
    for (int i = 0; i < 4; ++i){
      int flat = tid + i*256;
      int r = flat >> 3, c = flat & 7;
      long ra = GATHER ? (long)idx[m0 + r] : (long)(m0 + r);
      gll16(Ab + ra*(long)ldA + c*8, &As[flat*8]);
      gll16(Bb + (long)(n0 + r)*ldB + c*8, &Bs[flat*8]);
    }
    __syncthreads();
    bf16x8 af[2][4], bfr[2][4];
    #pragma unroll
    for (int kk = 0; kk < 2; ++kk){
      #pragma unroll
      for (int mi = 0; mi < 4; ++mi)
        af[kk][mi] = *(const bf16x8*)&As[(wm*64 + mi*16 + (l & 15))*64 + kk*32 + ((l >> 4)*8)];
      #pragma unroll
      for (int ni = 0; ni < 4; ++ni)
        bfr[kk][ni] = *(const bf16x8*)&Bs[(wn*64 + ni*16 + (l & 15))*64 + kk*32 + ((l >> 4)*8)];
    }
    #pragma unroll
    for (int kk = 0; kk < 2; ++kk)
      #pragma unroll
      for (int mi = 0; mi < 4; ++mi)
        #pragma unroll
        for (int ni = 0; ni < 4; ++ni)
          acc[mi][ni] = __builtin_amdgcn_mfma_f32_16x16x32_bf16(af[kk][mi], bfr[kk][ni], acc[mi][ni], 0, 0, 0);
    __syncthreads();
  }

  // epilogue: D[row=(l>>4)*4+j][col=l&15] per fragment
  #pragma unroll
  for (int mi = 0; mi < 4; ++mi){
    #pragma unroll
    for (int ni = 0; ni < 4; ++ni){
      int col = n0 + wn*64 + ni*16 + (l & 15);
      float bsv = bias[col];
      #pragma unroll
      for (int j = 0; j < 4; ++j){
        int row = m0 + wm*64 + mi*16 + ((l >> 4)*4) + j;
        float v = acc[mi][ni][j] + bsv;
        if (EPI == 0){ v = fmaxf(v, 0.f); v = fminf(rintf(v*16.f)*0.0625f, 0.9375f); }
        out[(size_t)row*ldOut + col] = f2bf(v);
      }
    }
  }
}

// ---------------- linear scan (valid until first spike; detects first spike) ----------------

__global__ __launch_bounds__(256) void scan_k(const u16* __restrict__ I, const float* __restrict__ memin,
    float* __restrict__ memout, int* __restrict__ firstspike, int t0, int CH)
{
  int g = blockIdx.x*256 + threadIdx.x;   // 65536 threads: 2 h per thread
  int b = g >> 9;
  int h2 = g & 511;
  size_t base = ((size_t)b << 10) + ((size_t)h2 << 1);
  float m0 = memin[base], m1 = memin[base + 1];
  const u16* p = I + base;
  int fs = 0x7FFFFFFF;
  #pragma unroll 16
  for (int t = 0; t < CH; ++t){
    u32 v = *(const u32*)(p + ((size_t)t << 17));   // stride B_*H_ = 131072 elems
    m0 = 0.2f*m0 + bf2f((u16)(v & 0xFFFFu));
    m1 = 0.2f*m1 + bf2f((u16)(v >> 16));
    if (fmaxf(m0, m1) > 0.5f) fs = min(fs, t0 + t);
  }
  memout[base] = m0; memout[base + 1] = m1;
  if (fs != 0x7FFFFFFF) atomicMin(firstspike + b, fs);
}

// ---------------- exact fallback recurrence (runs only for batches that spiked) ----------------

__global__ __launch_bounds__(256) void fallback_k(const u16* __restrict__ I, const float* __restrict__ memstart,
    float* __restrict__ memtrue, float* __restrict__ spiketrue, float* __restrict__ sumspike,
    const float* __restrict__ qWr2T, int* __restrict__ active, const int* __restrict__ firstspike,
    int t0, int CH)
{
  const int b = blockIdx.x, tid = threadIdx.x;
  const bool wasact = (active[b] != 0);
  const int fs = firstspike[b];
  if (!wasact && fs >= t0 + CH) return;

  __shared__ int slist[H_];
  __shared__ int scount;
  float mem[4], sp[4], ss[4];
  #pragma unroll
  for (int j = 0; j < 4; ++j){
    int h = tid + j*256;
    size_t o = ((size_t)b << 10) + h;
    if (wasact){ mem[j] = memtrue[o]; sp[j] = spiketrue[o]; }
    else       { mem[j] = memstart[o]; sp[j] = 0.f; }
    ss[j] = sumspike[o];
  }
  for (int t = 0; t < CH; ++t){
    if (tid == 0) scount = 0;
    __syncthreads();
    #pragma unroll
    for (int j = 0; j < 4; ++j)
      if (sp[j] > 0.5f){ int k = atomicAdd(&scount, 1); slist[k] = tid + j*256; }
    __syncthreads();
    int sc = scount;
    #pragma unroll
    for (int j = 0; j < 4; ++j){
      int h = tid + j*256;
      float rec = 0.f;
      for (int u = 0; u < sc; ++u) rec += qWr2T[((size_t)slist[u] << 10) + h];
      float Iv = bf2f(I[(((size_t)t*B_ + b) << 10) + h]);
      mem[j] = mem[j]*0.2f*(1.f - sp[j]) + Iv + rec;
    }
    #pragma unroll
    for (int j = 0; j < 4; ++j){ float ns = (mem[j] > 0.5f) ? 1.f : 0.f; sp[j] = ns; ss[j] += ns; }
    __syncthreads();
  }
  #pragma unroll
  for (int j = 0; j < 4; ++j){
    size_t o = ((size_t)b << 10) + tid + j*256;
    memtrue[o] = mem[j]; spiketrue[o] = sp[j]; sumspike[o] = ss[j];
  }
  if (tid == 0 && !wasact) active[b] = 1;
}

// ---------------- final tiny GEMM ----------------

__global__ __launch_bounds__(256) void final_k(const float* __restrict__ ss, const float* __restrict__ W3,
    const float* __restrict__ b3, float* __restrict__ out)
{
  int b = blockIdx.x, tid = threadIdx.x;
  float p0 = 0.f, p1 = 0.f;
  for (int h = tid; h < H_; h += 256){
    float s = ss[((size_t)b << 10) + h];
    p0 += s*W3[h]; p1 += s*W3[H_ + h];
  }
  #pragma unroll
  for (int o = 32; o > 0; o >>= 1){ p0 += __shfl_down(p0, o, 64); p1 += __shfl_down(p1, o, 64); }
  __shared__ float r0[4], r1[4];
  if ((tid & 63) == 0){ r0[tid >> 6] = p0; r1[tid >> 6] = p1; }
  __syncthreads();
  if (tid == 0){
    out[b*2 + 0] = r0[0] + r0[1] + r0[2] + r0[3] + b3[0];
    out[b*2 + 1] = r1[0] + r1[1] + r1[2] + r1[3] + b3[1];
  }
}

// ---------------- host ----------------

extern "C" void kernel_launch(void* const* d_in, const int* in_sizes, int n_in,
                              void* d_out, int out_size, void* d_ws, size_t ws_size,
                              hipStream_t stream)
{
  (void)in_sizes; (void)n_in; (void)out_size;
  const int*   inputs = (const int*)  d_in[0];
  const float* emb    = (const float*)d_in[1];
  const float* W1     = (const float*)d_in[2];
  const float* b1     = (const float*)d_in[3];
  const float* W2     = (const float*)d_in[4];
  const float* b2     = (const float*)d_in[5];
  const float* Wr2    = (const float*)d_in[6];
  const float* br2    = (const float*)d_in[7];
  const float* W3     = (const float*)d_in[8];
  const float* b3     = (const float*)d_in[9];
  float* out = (float*)d_out;
  char* ws = (char*)d_ws;

  size_t off = 0;
  auto alloc = [&](size_t bytes)->char*{
    char* p = ws + off; off = (off + bytes + 255) & ~(size_t)255; return p;
  };
  u16*   embhi     = (u16*)  alloc((size_t)V_*EMBP_*2);
  u16*   emblo     = (u16*)  alloc((size_t)V_*EMBP_*2);
  u16*   w1hi      = (u16*)  alloc((size_t)E_*EMBP_*2);
  u16*   w1lo      = (u16*)  alloc((size_t)E_*EMBP_*2);
  u16*   qW2       = (u16*)  alloc((size_t)H_*E_*2);
  float* qWr2T     = (float*)alloc((size_t)H_*H_*4);
  float* b2br2     = (float*)alloc((size_t)H_*4);
  int*   idx2      = (int*)  alloc((size_t)NTOK_*4);
  u16*   xq        = (u16*)  alloc((size_t)NTOK_*E_*2);
  float* memA      = (float*)alloc((size_t)B_*H_*4);
  float* memB      = (float*)alloc((size_t)B_*H_*4);
  float* memtrue   = (float*)alloc((size_t)B_*H_*4);
  float* spiketrue = (float*)alloc((size_t)B_*H_*4);
  float* sumspike  = (float*)alloc((size_t)B_*H_*4);
  int*   firstspk  = (int*)  alloc((size_t)B_*4);
  int*   active    = (int*)  alloc((size_t)B_*4);

  int CH = 1024;
  while (CH > 32 && off + (size_t)B_*CH*H_*2 > ws_size) CH >>= 1;
  u16* I = (u16*)alloc((size_t)B_*CH*H_*2);
  const int nch = S_ / CH;

  // state init (ws is poisoned before every call)
  hipMemsetAsync(memA,     0,    (size_t)B_*H_*4, stream);
  hipMemsetAsync(sumspike, 0,    (size_t)B_*H_*4, stream);
  hipMemsetAsync(active,   0,    (size_t)B_*4,    stream);
  hipMemsetAsync(firstspk, 0x7F, (size_t)B_*4,    stream);

  prep_emb_k<<<V_*EMBP_/256, 256, 0, stream>>>(emb, embhi, emblo);
  {
    const int total = E_*EMBP_ + H_*E_ + H_*H_ + H_ + NTOK_;
    prep_misc_k<<<(total + 255)/256, 256, 0, stream>>>(W1, W2, Wr2, b2, br2, inputs,
                                                       w1hi, w1lo, qW2, qWr2T, b2br2, idx2);
  }

  // GEMM1: xq = quant(relu(gather(emb_hi/lo) @ W1_hi/lo^T + b1)), 3-pass hi/lo split
  {
    GPlan p1;
    p1.A[0] = embhi;      p1.B[0] = w1hi;
    p1.A[1] = embhi + 64; p1.B[1] = w1hi + 64;
    p1.A[2] = embhi;      p1.B[2] = w1lo;
    p1.A[3] = embhi + 64; p1.B[3] = w1lo + 64;
    p1.A[4] = emblo;      p1.B[4] = w1hi;
    p1.A[5] = emblo + 64; p1.B[5] = w1hi + 64;
    gemm_k<0, true, 6><<<dim3(NTOK_/128, E_/128), 256, 0, stream>>>(
        p1, idx2, EMBP_, EMBP_, b1, xq, E_);
  }

  // chunked: GEMM2 (I = xq @ qW2^T + b2 + br2) -> linear scan -> fallback
  float* mi_ = memA;
  float* mo_ = memB;
  for (int c = 0; c < nch; ++c){
    const u16* xrow = xq + (size_t)c*CH*B_*E_;
    GPlan p2;
    for (int s = 0; s < 4; ++s){ p2.A[s] = xrow + s*64; p2.B[s] = qW2 + s*64; }
    p2.A[4] = p2.A[5] = xrow; p2.B[4] = p2.B[5] = qW2;
    gemm_k<1, false, 4><<<dim3(CH*B_/128, H_/128), 256, 0, stream>>>(
        p2, (const int*)nullptr, E_, E_, b2br2, I, H_);
    scan_k<<<(B_*H_/2)/256, 256, 0, stream>>>(I, mi_, mo_, firstspk, c*CH, CH);
    fallback_k<<<B_, 256, 0, stream>>>(I, mi_, memtrue, spiketrue, sumspike,
                                       qWr2T, active, firstspk, c*CH, CH);
    float* t = mi_; mi_ = mo_; mo_ = t;
  }

  final_k<<<B_, 256, 0, stream>>>(sumspike, W3, b3, out);
}

// Round 2
// 235.574 us; speedup vs baseline: 1.5247x; 1.5247x over previous
//
#include <hip/hip_runtime.h>
#include <stdint.h>

typedef unsigned short u16;
typedef unsigned int   u32;
typedef unsigned char  u8;
typedef signed char    s8;

#define B_    128
#define S_    1024
#define H_    1024
#define E_    256
#define EMB_  100
#define EMBP_ 128
#define V_    50000
#define NTOK_ (B_*S_)
#define FSINF 0x7F7F7F7F

typedef __attribute__((ext_vector_type(8))) short bf16x8;
typedef __attribute__((ext_vector_type(4))) float f32x4;
typedef __attribute__((ext_vector_type(4))) int   i32x4;

__device__ __forceinline__ float bf2f(u16 u){ union{u32 i; float f;} c; c.i=((u32)u)<<16; return c.f; }
__device__ __forceinline__ u16 f2bf(float f){ u32 x=__float_as_uint(f); return (u16)((x + 0x7FFFu + ((x>>16)&1u))>>16); }

__device__ __forceinline__ void gll16(const void* g, void* l){
  __builtin_amdgcn_global_load_lds((const __attribute__((address_space(1))) void*)g,
                                   (__attribute__((address_space(3))) void*)l, 16, 0, 0);
}

// ---------------- prep kernels ----------------

__global__ __launch_bounds__(256) void prep_emb_k(const float* __restrict__ emb,
                                                  u16* __restrict__ hi){
  const int n = V_*EMBP_;
  for (int i = blockIdx.x*256 + threadIdx.x; i < n; i += gridDim.x*256){
    int v = i >> 7, k = i & 127;
    float val = (k < EMB_) ? emb[v*EMB_ + k] : 0.f;
    hi[i] = f2bf(val);
  }
}

__global__ __launch_bounds__(256) void prep_misc_k(const float* __restrict__ W1, const float* __restrict__ W2,
    const float* __restrict__ Wr2, const float* __restrict__ b2, const float* __restrict__ br2,
    u16* __restrict__ w1hi, s8* __restrict__ qW2i, float* __restrict__ qWr2T, float* __restrict__ b2br2){
  const int N1 = E_*EMBP_;      // 32768   W1 bf16 pad
  const int N2 = H_*E_;         // 262144  qW2 as int8 (x16)
  const int N3 = H_*H_;         // 1048576 qWr2 transposed f32
  const int N4 = H_;            // 1024    b2+br2
  const int total = N1+N2+N3+N4;
  for (int i = blockIdx.x*256 + threadIdx.x; i < total; i += gridDim.x*256){
    int j = i;
    if (j < N1){
      int n = j >> 7, k = j & 127;
      float val = (k < EMB_) ? W1[n*EMB_ + k] : 0.f;
      w1hi[j] = f2bf(val);
    } else if ((j -= N1) < N2){
      float q = rintf(W2[j]*16.f);
      q = fminf(fmaxf(q, -15.f), 15.f);
      qW2i[j] = (s8)(int)q;
    } else if ((j -= N2) < N3){
      int hp = j >> 10, h = j & 1023;
      float q = rintf(Wr2[h*H_ + hp]*16.f)*0.0625f;
      qWr2T[j] = fminf(fmaxf(q, -0.9375f), 0.9375f);
    } else {
      j -= N3;
      b2br2[j] = b2[j] + br2[j];
    }
  }
}

// ---------------- GEMM1: xq = quant(relu(gather(emb) @ W1^T + b1)) as int8 (x16) ----------------
// tiles 128x128, K=128 (2 k-steps of 64), bf16 MFMA, XOR-swizzled LDS.

__global__ __launch_bounds__(256) void gemm1_k(const int* __restrict__ inputs,
    const u16* __restrict__ embhi, const u16* __restrict__ w1hi,
    const float* __restrict__ b1, u8* __restrict__ xq)
{
  __shared__ __align__(16) char As[16384];
  __shared__ __align__(16) char Bs[16384];
  const int tid = threadIdx.x;
  const int m0 = blockIdx.x*128, n0 = blockIdx.y*128;
  const int l = tid & 63, wid = tid >> 6;
  const int wm = wid >> 1, wn = wid & 1;

  f32x4 acc[4][4];
  #pragma unroll
  for (int a = 0; a < 4; ++a)
    #pragma unroll
    for (int c = 0; c < 4; ++c)
      acc[a][c] = (f32x4)0.f;

  #pragma unroll
  for (int st = 0; st < 2; ++st){
    #pragma unroll
    for (int i = 0; i < 4; ++i){
      int p = tid + i*256, r = p >> 3, c = p & 7;
      int sw = st*128 + ((c ^ (r & 7)) * 16);
      long ga = (long)inputs[m0 + r];
      gll16((const char*)embhi + ga*256 + sw, As + p*16);
      gll16((const char*)w1hi + (long)(n0 + r)*256 + sw, Bs + p*16);
    }
    __syncthreads();
    bf16x8 af[2][4], bfv[2][4];
    #pragma unroll
    for (int kk = 0; kk < 2; ++kk){
      #pragma unroll
      for (int mi = 0; mi < 4; ++mi){
        int rA = wm*64 + mi*16 + (l & 15);
        af[kk][mi] = *(const bf16x8*)&As[rA*128 + (((kk*4 + (l >> 4)) ^ (rA & 7)) * 16)];
      }
      #pragma unroll
      for (int ni = 0; ni < 4; ++ni){
        int rB = wn*64 + ni*16 + (l & 15);
        bfv[kk][ni] = *(const bf16x8*)&Bs[rB*128 + (((kk*4 + (l >> 4)) ^ (rB & 7)) * 16)];
      }
    }
    #pragma unroll
    for (int kk = 0; kk < 2; ++kk)
      #pragma unroll
      for (int mi = 0; mi < 4; ++mi)
        #pragma unroll
        for (int ni = 0; ni < 4; ++ni)
          acc[mi][ni] = __builtin_amdgcn_mfma_f32_16x16x32_bf16(af[kk][mi], bfv[kk][ni], acc[mi][ni], 0, 0, 0);
    __syncthreads();
  }

  #pragma unroll
  for (int mi = 0; mi < 4; ++mi){
    #pragma unroll
    for (int ni = 0; ni < 4; ++ni){
      int col = n0 + wn*64 + ni*16 + (l & 15);
      float bv = b1[col];
      #pragma unroll
      for (int j = 0; j < 4; ++j){
        int row = m0 + wm*64 + mi*16 + ((l >> 4)*4) + j;
        float v = fmaxf(acc[mi][ni][j] + bv, 0.f);
        int q = (int)rintf(v*16.f);
        q = (q > 15) ? 15 : q;
        xq[(size_t)row*E_ + col] = (u8)q;
      }
    }
  }
}

// ---------------- fused GEMM2 + membrane scan (no I materialization) ----------------
// block = (batch b, 128-h slice). Loops 8 t-subtiles of 128; i8 MFMA K=256;
// acc -> LDS (union with As/Bs) -> 128 threads run sequential decay filter,
// tracking first threshold crossing per batch (exact until first spike).

__global__ __launch_bounds__(256) void gemm2_k(const s8* __restrict__ xq,
    const s8* __restrict__ qW2i, const float* __restrict__ b2br2, int* __restrict__ firstspike)
{
  __shared__ __align__(16) char LB[32768];
  char* As = LB;
  char* Bs = LB + 16384;
  u16*  Sc = (u16*)LB;             // union: reused after MFMA phase each subtile
  const int tid = threadIdx.x;
  const int b = blockIdx.x, n0 = blockIdx.y*128;
  const int l = tid & 63, wid = tid >> 6;
  const int wm = wid >> 1, wn = wid & 1;

  float mem = 0.f, bias = 0.f;
  int fs = FSINF;
  if (tid < 128) bias = b2br2[n0 + tid];
  const s8* Ab0 = xq + (size_t)b*S_*E_;

  for (int sub = 0; sub < 8; ++sub){
    i32x4 acc[4][4];
    #pragma unroll
    for (int a = 0; a < 4; ++a)
      #pragma unroll
      for (int c = 0; c < 4; ++c)
        acc[a][c] = (i32x4)0;

    const s8* Ab = Ab0 + (size_t)sub*128*E_;
    #pragma unroll
    for (int ro = 0; ro < 2; ++ro){
      #pragma unroll
      for (int i = 0; i < 4; ++i){
        int p = tid + i*256, r = p >> 3, c = p & 7;
        int sw = ro*128 + ((c ^ (r & 7)) * 16);
        gll16(Ab + (long)r*E_ + sw, As + p*16);
        gll16(qW2i + (long)(n0 + r)*E_ + sw, Bs + p*16);
      }
      __syncthreads();
      #pragma unroll
      for (int kl = 0; kl < 2; ++kl){
        i32x4 af[4], bfv[4];
        #pragma unroll
        for (int mi = 0; mi < 4; ++mi){
          int rA = wm*64 + mi*16 + (l & 15);
          af[mi] = *(const i32x4*)&As[rA*128 + (((kl*4 + (l >> 4)) ^ (rA & 7)) * 16)];
        }
        #pragma unroll
        for (int ni = 0; ni < 4; ++ni){
          int rB = wn*64 + ni*16 + (l & 15);
          bfv[ni] = *(const i32x4*)&Bs[rB*128 + (((kl*4 + (l >> 4)) ^ (rB & 7)) * 16)];
        }
        #pragma unroll
        for (int mi = 0; mi < 4; ++mi)
          #pragma unroll
          for (int ni = 0; ni < 4; ++ni)
            acc[mi][ni] = __builtin_amdgcn_mfma_i32_16x16x64_i8(af[mi], bfv[ni], acc[mi][ni], 0, 0, 0);
      }
      __syncthreads();
    }

    // acc -> Sc  (As/Bs contents dead; barrier above guarantees reads done)
    #pragma unroll
    for (int mi = 0; mi < 4; ++mi)
      #pragma unroll
      for (int ni = 0; ni < 4; ++ni){
        int h = wn*64 + ni*16 + (l & 15);
        #pragma unroll
        for (int j = 0; j < 4; ++j){
          int t = wm*64 + mi*16 + ((l >> 4)*4) + j;
          Sc[t*128 + h] = f2bf((float)acc[mi][ni][j] * (1.f/256.f));
        }
      }
    __syncthreads();

    if (tid < 128){
      #pragma unroll 8
      for (int t = 0; t < 128; ++t){
        float v = bf2f(Sc[t*128 + tid]) + bias;
        mem = fmaf(mem, 0.2f, v);
        if (mem > 0.5f && fs == FSINF) fs = sub*128 + t;
      }
    }
    __syncthreads();
  }
  if (tid < 128 && fs != FSINF) atomicMin(&firstspike[b], fs);
}

// ---------------- exact fallback (only batches that spiked; recomputes I from xq) ----------------

__global__ __launch_bounds__(256) void fallback_k(const s8* __restrict__ xq, const s8* __restrict__ qW2i,
    const float* __restrict__ b2br2, const float* __restrict__ qWr2T,
    const int* __restrict__ firstspike, float* __restrict__ sumspike)
{
  const int b = blockIdx.x;
  if (firstspike[b] >= S_) return;          // clean batch: sumspike stays 0
  const int tid = threadIdx.x;
  __shared__ int slist[H_];
  __shared__ int scount;
  __shared__ s8 xrow[E_];
  float mem[4] = {0,0,0,0}, sp[4] = {0,0,0,0}, ss[4] = {0,0,0,0};

  for (int t = 0; t < S_; ++t){
    if (tid == 0) scount = 0;
    __syncthreads();
    #pragma unroll
    for (int j = 0; j < 4; ++j)
      if (sp[j] > 0.5f){ int k = atomicAdd(&scount, 1); slist[k] = tid + j*256; }
    if (tid < 64) ((int*)xrow)[tid] = ((const int*)(xq + (size_t)(b*S_ + t)*E_))[tid];
    __syncthreads();
    int sc = scount;
    #pragma unroll
    for (int j = 0; j < 4; ++j){
      int h = tid + j*256;
      const s8* wr = qW2i + (size_t)h*E_;
      int ia = 0;
      #pragma unroll 4
      for (int k = 0; k < E_; k += 4){
        ia += (int)xrow[k]*(int)wr[k] + (int)xrow[k+1]*(int)wr[k+1]
            + (int)xrow[k+2]*(int)wr[k+2] + (int)xrow[k+3]*(int)wr[k+3];
      }
      float Iv = (float)ia*(1.f/256.f) + b2br2[h];
      float rec = 0.f;
      for (int u = 0; u < sc; ++u) rec += qWr2T[((size_t)slist[u] << 10) + h];
      mem[j] = mem[j]*0.2f*(1.f - sp[j]) + Iv + rec;
    }
    #pragma unroll
    for (int j = 0; j < 4; ++j){ float ns = (mem[j] > 0.5f) ? 1.f : 0.f; sp[j] = ns; ss[j] += ns; }
    __syncthreads();
  }
  #pragma unroll
  for (int j = 0; j < 4; ++j)
    sumspike[((size_t)b << 10) + tid + j*256] = ss[j];
}

// ---------------- final tiny GEMM ----------------

__global__ __launch_bounds__(256) void final_k(const float* __restrict__ ss, const float* __restrict__ W3,
    const float* __restrict__ b3, float* __restrict__ out)
{
  int b = blockIdx.x, tid = threadIdx.x;
  float p0 = 0.f, p1 = 0.f;
  for (int h = tid; h < H_; h += 256){
    float s = ss[((size_t)b << 10) + h];
    p0 += s*W3[h]; p1 += s*W3[H_ + h];
  }
  #pragma unroll
  for (int o = 32; o > 0; o >>= 1){ p0 += __shfl_down(p0, o, 64); p1 += __shfl_down(p1, o, 64); }
  __shared__ float r0[4], r1[4];
  if ((tid & 63) == 0){ r0[tid >> 6] = p0; r1[tid >> 6] = p1; }
  __syncthreads();
  if (tid == 0){
    out[b*2 + 0] = r0[0] + r0[1] + r0[2] + r0[3] + b3[0];
    out[b*2 + 1] = r1[0] + r1[1] + r1[2] + r1[3] + b3[1];
  }
}

// ---------------- host ----------------

extern "C" void kernel_launch(void* const* d_in, const int* in_sizes, int n_in,
                              void* d_out, int out_size, void* d_ws, size_t ws_size,
                              hipStream_t stream)
{
  (void)in_sizes; (void)n_in; (void)out_size; (void)ws_size;
  const int*   inputs = (const int*)  d_in[0];
  const float* emb    = (const float*)d_in[1];
  const float* W1     = (const float*)d_in[2];
  const float* b1     = (const float*)d_in[3];
  const float* W2     = (const float*)d_in[4];
  const float* b2     = (const float*)d_in[5];
  const float* Wr2    = (const float*)d_in[6];
  const float* br2    = (const float*)d_in[7];
  const float* W3     = (const float*)d_in[8];
  const float* b3     = (const float*)d_in[9];
  float* out = (float*)d_out;
  char* ws = (char*)d_ws;

  size_t off = 0;
  auto alloc = [&](size_t bytes)->char*{
    char* p = ws + off; off = (off + bytes + 255) & ~(size_t)255; return p;
  };
  u16*   embhi    = (u16*)  alloc((size_t)V_*EMBP_*2);   // 12.8 MB
  u16*   w1hi     = (u16*)  alloc((size_t)E_*EMBP_*2);   // 64 KB
  s8*    qW2i     = (s8*)   alloc((size_t)H_*E_);        // 256 KB
  float* qWr2T    = (float*)alloc((size_t)H_*H_*4);      // 4 MB
  float* b2br2    = (float*)alloc((size_t)H_*4);
  u8*    xq       = (u8*)   alloc((size_t)NTOK_*E_);     // 32 MB
  float* sumspike = (float*)alloc((size_t)B_*H_*4);
  int*   firstspk = (int*)  alloc((size_t)B_*4);

  hipMemsetAsync(sumspike, 0,    (size_t)B_*H_*4, stream);
  hipMemsetAsync(firstspk, 0x7F, (size_t)B_*4,    stream);

  prep_emb_k<<<V_*EMBP_/256, 256, 0, stream>>>(emb, embhi);
  {
    const int total = E_*EMBP_ + H_*E_ + H_*H_ + H_;
    prep_misc_k<<<(total + 255)/256, 256, 0, stream>>>(W1, W2, Wr2, b2, br2,
                                                       w1hi, qW2i, qWr2T, b2br2);
  }
  gemm1_k<<<dim3(NTOK_/128, E_/128), 256, 0, stream>>>(inputs, embhi, w1hi, b1, xq);
  gemm2_k<<<dim3(B_, H_/128), 256, 0, stream>>>((const s8*)xq, qW2i, b2br2, firstspk);
  fallback_k<<<B_, 256, 0, stream>>>((const s8*)xq, qW2i, b2br2, qWr2T, firstspk, sumspike);
  final_k<<<B_, 256, 0, stream>>>(sumspike, W3, b3, out);
}

// Round 3
// 165.892 us; speedup vs baseline: 2.1651x; 1.4200x over previous
//
#include <hip/hip_runtime.h>
#include <stdint.h>

typedef unsigned short u16;
typedef unsigned int   u32;
typedef unsigned char  u8;
typedef signed char    s8;

#define B_    128
#define S_    1024
#define H_    1024
#define E_    256
#define EMB_  100
#define EMBP_ 128
#define V_    50000
#define NTOK_ (B_*S_)
#define FSINF 0x7F7F7F7F

typedef __attribute__((ext_vector_type(8))) short bf16x8;
typedef __attribute__((ext_vector_type(4))) float f32x4;
typedef __attribute__((ext_vector_type(4))) int   i32x4;

__device__ __forceinline__ u16 f2bf(float f){ u32 x=__float_as_uint(f); return (u16)((x + 0x7FFFu + ((x>>16)&1u))>>16); }
__device__ __forceinline__ float quantw(float w){ float r = rintf(w*16.f)*0.0625f; return fminf(fmaxf(r,-0.9375f),0.9375f); }

__device__ __forceinline__ void gll16(const void* g, void* l){
  __builtin_amdgcn_global_load_lds((const __attribute__((address_space(1))) void*)g,
                                   (__attribute__((address_space(3))) void*)l, 16, 0, 0);
}

// ---------------- merged prep ----------------

__global__ __launch_bounds__(256) void prep_all_k(const float* __restrict__ emb,
    const float* __restrict__ W1, const float* __restrict__ W2,
    const float* __restrict__ b2, const float* __restrict__ br2,
    u16* __restrict__ embhi, u16* __restrict__ w1hi, s8* __restrict__ qW2i,
    float* __restrict__ b2br2)
{
  int j = blockIdx.x*256 + threadIdx.x;
  const int N0 = V_*EMBP_;
  const int N1 = E_*EMBP_;
  const int N2 = H_*E_;
  const int N3 = H_;
  if (j < N0){
    int v = j >> 7, k = j & 127;
    embhi[j] = f2bf((k < EMB_) ? emb[v*EMB_ + k] : 0.f);
  } else if ((j -= N0) < N1){
    int n = j >> 7, k = j & 127;
    w1hi[j] = f2bf((k < EMB_) ? W1[n*EMB_ + k] : 0.f);
  } else if ((j -= N1) < N2){
    float q = rintf(W2[j]*16.f);
    qW2i[j] = (s8)(int)fminf(fmaxf(q, -15.f), 15.f);
  } else if ((j -= N2) < N3){
    b2br2[j] = b2[j] + br2[j];
  }
}

// ---------------- GEMM1: xq = quant(relu(gather(emb) @ W1^T + b1)) as int8 (x16) ----------------
// 128x128 tiles, K=128, bf16 MFMA, XOR-swizzled LDS. Block remap: the two n-blocks of
// each m-row land on the same XCD, temporally adjacent -> gathered emb rows hit L2 twice.

__global__ __launch_bounds__(256) void gemm1_k(const int* __restrict__ inputs,
    const u16* __restrict__ embhi, const u16* __restrict__ w1hi,
    const float* __restrict__ b1, u8* __restrict__ xq)
{
  __shared__ __align__(16) char As[16384];
  __shared__ __align__(16) char Bs[16384];
  const int tid = threadIdx.x;
  const int bx = blockIdx.x;
  const int n0 = ((bx >> 3) & 1) * 128;
  const int m0 = (((bx & 7) << 7) + (bx >> 4)) * 128;
  const int l = tid & 63, wid = tid >> 6;
  const int wm = wid >> 1, wn = wid & 1;

  f32x4 acc[4][4];
  #pragma unroll
  for (int a = 0; a < 4; ++a)
    #pragma unroll
    for (int c = 0; c < 4; ++c)
      acc[a][c] = (f32x4)0.f;

  #pragma unroll
  for (int st = 0; st < 2; ++st){
    #pragma unroll
    for (int i = 0; i < 4; ++i){
      int p = tid + i*256, r = p >> 3, c = p & 7;
      int sw = st*128 + ((c ^ (r & 7)) * 16);
      long ga = (long)inputs[m0 + r];
      gll16((const char*)embhi + ga*256 + sw, As + p*16);
      gll16((const char*)w1hi + (long)(n0 + r)*256 + sw, Bs + p*16);
    }
    __syncthreads();
    bf16x8 af[2][4], bfv[2][4];
    #pragma unroll
    for (int kk = 0; kk < 2; ++kk){
      #pragma unroll
      for (int mi = 0; mi < 4; ++mi){
        int rA = wm*64 + mi*16 + (l & 15);
        af[kk][mi] = *(const bf16x8*)&As[rA*128 + (((kk*4 + (l >> 4)) ^ (rA & 7)) * 16)];
      }
      #pragma unroll
      for (int ni = 0; ni < 4; ++ni){
        int rB = wn*64 + ni*16 + (l & 15);
        bfv[kk][ni] = *(const bf16x8*)&Bs[rB*128 + (((kk*4 + (l >> 4)) ^ (rB & 7)) * 16)];
      }
    }
    #pragma unroll
    for (int kk = 0; kk < 2; ++kk)
      #pragma unroll
      for (int mi = 0; mi < 4; ++mi)
        #pragma unroll
        for (int ni = 0; ni < 4; ++ni)
          acc[mi][ni] = __builtin_amdgcn_mfma_f32_16x16x32_bf16(af[kk][mi], bfv[kk][ni], acc[mi][ni], 0, 0, 0);
    __syncthreads();
  }

  #pragma unroll
  for (int mi = 0; mi < 4; ++mi){
    #pragma unroll
    for (int ni = 0; ni < 4; ++ni){
      int col = n0 + wn*64 + ni*16 + (l & 15);
      float bv = b1[col];
      #pragma unroll
      for (int j = 0; j < 4; ++j){
        int row = m0 + wm*64 + mi*16 + ((l >> 4)*4) + j;
        float v = fmaxf(acc[mi][ni][j] + bv, 0.f);
        int q = (int)rintf(v*16.f);
        q = (q > 15) ? 15 : q;
        xq[(size_t)row*E_ + col] = (u8)q;
      }
    }
  }
}

// ---------------- fused GEMM2 + parallel membrane scan ----------------
// block = (batch b, 128-h slice); B slice resident in VGPRs; A double-buffered;
// 16 subtiles of 64 t; scan: 128h x 2 chunks, exact carry + 16-step warm-up.

__global__ __launch_bounds__(256, 2) void gemm2_k(const s8* __restrict__ xq,
    const s8* __restrict__ qW2i, const float* __restrict__ b2br2, int* __restrict__ firstspike)
{
  __shared__ __align__(16) char LB[66560];   // [0,32K): A dbuf (B stage at init); [32K,64K): Sc f32 [128h][64t]; [64K,+1K): carry[2][128]
  float* carry = (float*)(LB + 65536);

  const int tid = threadIdx.x;
  const int bx  = blockIdx.x;
  const int xcd = bx & 7, idx = bx >> 3;
  const int b   = xcd*16 + (idx >> 3);       // all 8 n-slices of a batch on one XCD
  const int n0  = (idx & 7) * 128;
  const int l = tid & 63, wid = tid >> 6;
  const int wm = wid >> 1, wn = wid & 1;

  // stage B slice (128h x 256k i8) pre-inverse-swizzled
  #pragma unroll
  for (int i = 0; i < 8; ++i){
    int p = tid + i*256, r = p >> 4, g = p & 15;
    gll16(qW2i + (size_t)(n0 + r)*256 + ((g ^ (r & 7))*16), LB + p*16);
  }
  __syncthreads();

  // B fragments -> registers (persist across all subtiles)
  i32x4 bq[4][4];
  #pragma unroll
  for (int ni = 0; ni < 4; ++ni){
    int rB = wn*64 + ni*16 + (l & 15);
    #pragma unroll
    for (int ks = 0; ks < 4; ++ks){
      int g = (ks*4 + (l >> 4)) ^ (rB & 7);
      bq[ni][ks] = *(const i32x4*)&LB[rB*256 + g*16];
    }
  }
  float bias_e[4];
  #pragma unroll
  for (int ni = 0; ni < 4; ++ni)
    bias_e[ni] = b2br2[n0 + wn*64 + ni*16 + (l & 15)];
  if (tid < 128) carry[tid] = 0.f;
  __syncthreads();                                   // B frags consumed -> may overwrite

  // stage A(0)
  const s8* Ab0 = xq + (size_t)b*S_*E_;
  #pragma unroll
  for (int i = 0; i < 4; ++i){
    int p = tid + i*256, r = p >> 4, g = p & 15;
    gll16(Ab0 + (size_t)r*256 + ((g ^ (r & 7))*16), LB + p*16);
  }
  __syncthreads();

  const int hsc = tid & 127, chunk = tid >> 7;
  const int hx = hsc & 15;
  float mmax = -1e30f;

  for (int s = 0; s < 16; ++s){
    const char* Acur = LB + (s & 1)*16384;
    i32x4 aq[2][4];
    #pragma unroll
    for (int mi = 0; mi < 2; ++mi){
      int rA = wm*32 + mi*16 + (l & 15);
      #pragma unroll
      for (int ks = 0; ks < 4; ++ks){
        int g = (ks*4 + (l >> 4)) ^ (rA & 7);
        aq[mi][ks] = *(const i32x4*)&Acur[rA*256 + g*16];
      }
    }
    // prefetch next A tile into the other buffer (drained by end-of-iter barrier)
    if (s < 15){
      const s8* Ab = Ab0 + (size_t)(s + 1)*64*256;
      char* dst = LB + ((s + 1) & 1)*16384;
      #pragma unroll
      for (int i = 0; i < 4; ++i){
        int p = tid + i*256, r = p >> 4, g = p & 15;
        gll16(Ab + (size_t)r*256 + ((g ^ (r & 7))*16), dst + p*16);
      }
    }
    i32x4 acc[2][4];
    #pragma unroll
    for (int mi = 0; mi < 2; ++mi)
      #pragma unroll
      for (int ni = 0; ni < 4; ++ni)
        acc[mi][ni] = (i32x4)0;
    #pragma unroll
    for (int ks = 0; ks < 4; ++ks)
      #pragma unroll
      for (int mi = 0; mi < 2; ++mi)
        #pragma unroll
        for (int ni = 0; ni < 4; ++ni)
          acc[mi][ni] = __builtin_amdgcn_mfma_i32_16x16x64_i8(aq[mi][ks], bq[ni][ks], acc[mi][ni], 0, 0, 0);

    // epilogue: I = acc/256 + bias -> Sc [h][t] f32, granule-XOR swizzle, b128 stores
    #pragma unroll
    for (int mi = 0; mi < 2; ++mi){
      int g = wm*8 + mi*4 + (l >> 4);
      int gp = g ^ (l & 15);
      #pragma unroll
      for (int ni = 0; ni < 4; ++ni){
        int h = wn*64 + ni*16 + (l & 15);
        f32x4 w;
        #pragma unroll
        for (int jj = 0; jj < 4; ++jj)
          w[jj] = fmaf((float)acc[mi][ni][jj], 0.00390625f, bias_e[ni]);
        *(f32x4*)&LB[32768 + h*256 + gp*16] = w;
      }
    }
    __syncthreads();

    // scan: chunk0 = t[0..31] from exact carry; chunk1 = warm t[16..31] then live t[32..63]
    const char* sb = LB + 32768 + hsc*256;
    if (chunk == 0){
      float m = carry[(s & 1)*128 + hsc];
      #pragma unroll
      for (int gi = 0; gi < 8; ++gi){
        f32x4 v = *(const f32x4*)(sb + ((gi ^ hx)*16));
        #pragma unroll
        for (int jj = 0; jj < 4; ++jj){ m = fmaf(m, 0.2f, v[jj]); mmax = fmaxf(mmax, m); }
      }
    } else {
      float m = 0.f;
      #pragma unroll
      for (int gi = 4; gi < 8; ++gi){
        f32x4 v = *(const f32x4*)(sb + ((gi ^ hx)*16));
        #pragma unroll
        for (int jj = 0; jj < 4; ++jj) m = fmaf(m, 0.2f, v[jj]);
      }
      #pragma unroll
      for (int gi = 8; gi < 16; ++gi){
        f32x4 v = *(const f32x4*)(sb + ((gi ^ hx)*16));
        #pragma unroll
        for (int jj = 0; jj < 4; ++jj){ m = fmaf(m, 0.2f, v[jj]); mmax = fmaxf(mmax, m); }
      }
      carry[((s + 1) & 1)*128 + hsc] = m;
    }
    __syncthreads();
  }
  if (mmax > 0.5f) atomicMin(&firstspike[b], 0);
}

// ---------------- exact fallback (spiking batches only; quantizes Wr2 on the fly) ----------------

__global__ __launch_bounds__(256) void fallback_k(const s8* __restrict__ xq, const s8* __restrict__ qW2i,
    const float* __restrict__ b2br2, const float* __restrict__ Wr2,
    const int* __restrict__ firstspike, float* __restrict__ sumspike)
{
  const int b = blockIdx.x;
  if (firstspike[b] >= S_) return;
  const int tid = threadIdx.x;
  __shared__ int slist[H_];
  __shared__ int scount;
  __shared__ s8 xrow[E_];
  float mem[4] = {0,0,0,0}, sp[4] = {0,0,0,0}, ss[4] = {0,0,0,0};

  for (int t = 0; t < S_; ++t){
    if (tid == 0) scount = 0;
    __syncthreads();
    #pragma unroll
    for (int j = 0; j < 4; ++j)
      if (sp[j] > 0.5f){ int k = atomicAdd(&scount, 1); slist[k] = tid + j*256; }
    if (tid < 64) ((int*)xrow)[tid] = ((const int*)(xq + (size_t)(b*S_ + t)*E_))[tid];
    __syncthreads();
    int sc = scount;
    #pragma unroll
    for (int j = 0; j < 4; ++j){
      int h = tid + j*256;
      const s8* wr = qW2i + (size_t)h*E_;
      int ia = 0;
      #pragma unroll 4
      for (int k = 0; k < E_; k += 4){
        ia += (int)xrow[k]*(int)wr[k] + (int)xrow[k+1]*(int)wr[k+1]
            + (int)xrow[k+2]*(int)wr[k+2] + (int)xrow[k+3]*(int)wr[k+3];
      }
      float Iv = (float)ia*(1.f/256.f) + b2br2[h];
      float rec = 0.f;
      for (int u = 0; u < sc; ++u) rec += quantw(Wr2[(size_t)h*H_ + slist[u]]);
      mem[j] = mem[j]*0.2f*(1.f - sp[j]) + Iv + rec;
    }
    #pragma unroll
    for (int j = 0; j < 4; ++j){ float ns = (mem[j] > 0.5f) ? 1.f : 0.f; sp[j] = ns; ss[j] += ns; }
    __syncthreads();
  }
  #pragma unroll
  for (int j = 0; j < 4; ++j)
    sumspike[((size_t)b << 10) + tid + j*256] = ss[j];
}

// ---------------- final tiny GEMM ----------------

__global__ __launch_bounds__(256) void final_k(const float* __restrict__ ss, const float* __restrict__ W3,
    const float* __restrict__ b3, float* __restrict__ out)
{
  int b = blockIdx.x, tid = threadIdx.x;
  float p0 = 0.f, p1 = 0.f;
  for (int h = tid; h < H_; h += 256){
    float s = ss[((size_t)b << 10) + h];
    p0 += s*W3[h]; p1 += s*W3[H_ + h];
  }
  #pragma unroll
  for (int o = 32; o > 0; o >>= 1){ p0 += __shfl_down(p0, o, 64); p1 += __shfl_down(p1, o, 64); }
  __shared__ float r0[4], r1[4];
  if ((tid & 63) == 0){ r0[tid >> 6] = p0; r1[tid >> 6] = p1; }
  __syncthreads();
  if (tid == 0){
    out[b*2 + 0] = r0[0] + r0[1] + r0[2] + r0[3] + b3[0];
    out[b*2 + 1] = r1[0] + r1[1] + r1[2] + r1[3] + b3[1];
  }
}

// ---------------- host ----------------

extern "C" void kernel_launch(void* const* d_in, const int* in_sizes, int n_in,
                              void* d_out, int out_size, void* d_ws, size_t ws_size,
                              hipStream_t stream)
{
  (void)in_sizes; (void)n_in; (void)out_size; (void)ws_size;
  const int*   inputs = (const int*)  d_in[0];
  const float* emb    = (const float*)d_in[1];
  const float* W1     = (const float*)d_in[2];
  const float* b1     = (const float*)d_in[3];
  const float* W2     = (const float*)d_in[4];
  const float* b2     = (const float*)d_in[5];
  const float* Wr2    = (const float*)d_in[6];
  const float* br2    = (const float*)d_in[7];
  const float* W3     = (const float*)d_in[8];
  const float* b3     = (const float*)d_in[9];
  float* out = (float*)d_out;
  char* ws = (char*)d_ws;

  size_t off = 0;
  auto alloc = [&](size_t bytes)->char*{
    char* p = ws + off; off = (off + bytes + 255) & ~(size_t)255; return p;
  };
  u16*   embhi    = (u16*)  alloc((size_t)V_*EMBP_*2);   // 12.8 MB
  u16*   w1hi     = (u16*)  alloc((size_t)E_*EMBP_*2);
  s8*    qW2i     = (s8*)   alloc((size_t)H_*E_);
  float* b2br2    = (float*)alloc((size_t)H_*4);
  u8*    xq       = (u8*)   alloc((size_t)NTOK_*E_);     // 32 MB
  float* sumspike = (float*)alloc((size_t)B_*H_*4);
  int*   firstspk = (int*)  alloc((size_t)B_*4);

  hipMemsetAsync(sumspike, 0,    (size_t)B_*H_*4, stream);
  hipMemsetAsync(firstspk, 0x7F, (size_t)B_*4,    stream);

  {
    const int total = V_*EMBP_ + E_*EMBP_ + H_*E_ + H_;
    prep_all_k<<<(total + 255)/256, 256, 0, stream>>>(emb, W1, W2, b2, br2,
                                                      embhi, w1hi, qW2i, b2br2);
  }
  gemm1_k<<<2048, 256, 0, stream>>>(inputs, embhi, w1hi, b1, xq);
  gemm2_k<<<1024, 256, 0, stream>>>((const s8*)xq, qW2i, b2br2, firstspk);
  fallback_k<<<B_, 256, 0, stream>>>((const s8*)xq, qW2i, b2br2, Wr2, firstspk, sumspike);
  final_k<<<B_, 256, 0, stream>>>(sumspike, W3, b3, out);
}